// Round 1
// baseline (298.778 us; speedup 1.0000x reference)
//
#include <hip/hip_runtime.h>
#include <hip/hip_bf16.h>

// SE(3)-equivariant layer, MI355X / gfx950.
// Strategy: per-block = (64-edge tile) x (one path of 256 W2 columns).
//   Phase 1a: radial embedding emb[10], unit vector y1 (f32, LDS)
//             + stage W2 path-slice transposed to LDS as bf16  w2t[n][k]
//   Phase 1b: h = sqrt(2/10)*relu(emb@W1) -> bf16 LDS  hl[e][k]
//             + gather per-edge source features (x0 / z / x1) to LDS
//   Phase 2 : per wave (16 edges): for each u-tile (16 cols):
//             w = mfma_f32_16x16x32_bf16 x2 (K=64), contract over u in regs,
//             atomicAdd into out[dst].
// All scales (1/8 from W2, c=1/sqrt(32), N/E=0.0625, inv_sqrt3) folded at the end.

typedef __attribute__((ext_vector_type(8))) short bf16x8;
typedef __attribute__((ext_vector_type(4))) float f32x4;

#define TILE_E 64

__device__ __forceinline__ float sus_f(float t) {
    return t > 0.0f ? __expf(-1.0f / t) : 0.0f;
}

// f32 -> bf16 round-to-nearest-even
__device__ __forceinline__ unsigned short f2bf(float f) {
    unsigned int u = __float_as_uint(f);
    u += 0x7FFFu + ((u >> 16) & 1u);
    return (unsigned short)(u >> 16);
}

__global__ __launch_bounds__(256, 2) void se3_fused(
    const float* __restrict__ x,
    const float* __restrict__ edge_vec,
    const float* __restrict__ w1,
    const float* __restrict__ w2,
    const int* __restrict__ src,
    const int* __restrict__ dst,
    float* __restrict__ out)
{
    __shared__ unsigned short w2t[256][72];   // [n][k] bf16, path slice, +8 pad
    __shared__ unsigned short hl[TILE_E][72]; // [e][k] bf16, +8 pad
    __shared__ float embl[TILE_E][10];
    __shared__ float y1l[TILE_E][4];
    __shared__ float Gl[TILE_E][16];          // x0 (paths A,B) or z (path D)
    __shared__ float G3l[TILE_E][48];         // x1 (path C)

    const int tid  = threadIdx.x;
    const int path = blockIdx.x & 3;
    const int e0   = (blockIdx.x >> 2) * TILE_E;

    // ---- Phase 1a: radial embedding + unit vector ----
    const float C0 = 1.14136f * __expf(2.0f) * 3.1622776601683795f; // *sqrt(10)
    for (int idx = tid; idx < TILE_E * 10; idx += 256) {
        const int e = idx / 10, i = idx % 10;
        const float vx = edge_vec[(e0 + e) * 3 + 0];
        const float vy = edge_vec[(e0 + e) * 3 + 1];
        const float vz = edge_vec[(e0 + e) * 3 + 2];
        const float r  = sqrtf(vx * vx + vy * vy + vz * vz);
        const float diff = r * (11.0f / 4.5f) - (float)(i + 1);
        embl[e][i] = C0 * sus_f(diff + 1.0f) * sus_f(1.0f - diff);
        if (i == 0) {
            const float s = 1.7320508075688772f / r;
            y1l[e][0] = vx * s; y1l[e][1] = vy * s; y1l[e][2] = vz * s;
        }
    }

    // ---- Stage W2 path slice, transposed, bf16: w2t[n][k] = w2[k][path*256+n]
    {
        const float* col = w2 + path * 256 + tid;  // coalesced across tid per k
        #pragma unroll 8
        for (int k = 0; k < 64; ++k)
            w2t[tid][k] = f2bf(col[k * 1024]);
    }
    __syncthreads();

    // ---- Phase 1b: h (bf16) + gathered source features ----
    for (int idx = tid; idx < TILE_E * 8; idx += 256) {
        const int e = idx / 8, j0 = (idx % 8) * 8;
        float acc[8];
        #pragma unroll
        for (int jj = 0; jj < 8; ++jj) acc[jj] = 0.0f;
        #pragma unroll
        for (int i = 0; i < 10; ++i) {
            const float ei = embl[e][i];
            #pragma unroll
            for (int jj = 0; jj < 8; ++jj)
                acc[jj] += ei * w1[i * 64 + j0 + jj];
        }
        unsigned int pk[4];
        #pragma unroll
        for (int p2 = 0; p2 < 4; ++p2) {
            const unsigned short lo = f2bf(fmaxf(acc[2*p2],   0.0f) * 0.4472135954999579f);
            const unsigned short hi = f2bf(fmaxf(acc[2*p2+1], 0.0f) * 0.4472135954999579f);
            pk[p2] = (unsigned int)lo | ((unsigned int)hi << 16);
        }
        uint4 v; v.x = pk[0]; v.y = pk[1]; v.z = pk[2]; v.w = pk[3];
        *(uint4*)&hl[e][j0] = v;
    }

    if (path == 2) {
        for (int idx = tid; idx < TILE_E * 48; idx += 256) {
            const int e = idx / 48, c = idx % 48;
            G3l[e][c] = x[(size_t)src[e0 + e] * 64 + 16 + c];
        }
    } else if (path == 3) {
        for (int idx = tid; idx < TILE_E * 16; idx += 256) {
            const int e = idx / 16, u = idx % 16;
            const float* xs = x + (size_t)src[e0 + e] * 64 + 16 + u * 3;
            Gl[e][u] = xs[0] * y1l[e][0] + xs[1] * y1l[e][1] + xs[2] * y1l[e][2];
        }
    } else {
        for (int idx = tid; idx < TILE_E * 16; idx += 256) {
            const int e = idx / 16, u = idx % 16;
            Gl[e][u] = x[(size_t)src[e0 + e] * 64 + u];
        }
    }
    __syncthreads();

    // ---- Phase 2: MFMA w-tiles + fused contraction over u ----
    const int lane = tid & 63;
    const int wv   = tid >> 6;        // wave id: m-tile (16 edges)
    const int lm   = lane & 15;       // = v (C col) and A/B row/col index
    const int q    = lane >> 4;
    const int erow = wv * 16;

    const bf16x8 a0 = *(const bf16x8*)&hl[erow + lm][8 * q];
    const bf16x8 a1 = *(const bf16x8*)&hl[erow + lm][32 + 8 * q];

    float accO[4]  = {0.f, 0.f, 0.f, 0.f};
    float accC0[4] = {0.f, 0.f, 0.f, 0.f};
    float accC1[4] = {0.f, 0.f, 0.f, 0.f};
    float accC2[4] = {0.f, 0.f, 0.f, 0.f};

    #pragma unroll 4
    for (int t = 0; t < 16; ++t) {     // t = u
        const bf16x8 b0 = *(const bf16x8*)&w2t[t * 16 + lm][8 * q];
        const bf16x8 b1 = *(const bf16x8*)&w2t[t * 16 + lm][32 + 8 * q];
        f32x4 wa = {0.f, 0.f, 0.f, 0.f};
        wa = __builtin_amdgcn_mfma_f32_16x16x32_bf16(a0, b0, wa, 0, 0, 0);
        wa = __builtin_amdgcn_mfma_f32_16x16x32_bf16(a1, b1, wa, 0, 0, 0);
        // lane holds w[e = erow+4q+r][u=t][v=lm]
        if (path == 2) {
            #pragma unroll
            for (int r2 = 0; r2 < 4; ++r2) {
                const int el = erow + 4 * q + r2;
                accC0[r2] += wa[r2] * G3l[el][t * 3 + 0];
                accC1[r2] += wa[r2] * G3l[el][t * 3 + 1];
                accC2[r2] += wa[r2] * G3l[el][t * 3 + 2];
            }
        } else {
            #pragma unroll
            for (int r2 = 0; r2 < 4; ++r2) {
                const int el = erow + 4 * q + r2;
                accO[r2] += wa[r2] * Gl[el][t];
            }
        }
    }

    // S = c * (1/8 from W2 scale) * (N/E)
    const float S = 0.17677669529663687f * 0.125f * 0.0625f;
    #pragma unroll
    for (int r2 = 0; r2 < 4; ++r2) {
        const int el = erow + 4 * q + r2;
        const int d  = dst[e0 + el];
        if (path == 0) {
            atomicAdd(&out[d * 64 + lm], S * accO[r2]);
        } else if (path == 3) {
            atomicAdd(&out[d * 64 + lm], S * 0.5773502691896258f * accO[r2]);
        } else if (path == 1) {
            const float tv = S * accO[r2];
            atomicAdd(&out[d * 64 + 16 + lm * 3 + 0], tv * y1l[el][0]);
            atomicAdd(&out[d * 64 + 16 + lm * 3 + 1], tv * y1l[el][1]);
            atomicAdd(&out[d * 64 + 16 + lm * 3 + 2], tv * y1l[el][2]);
        } else {
            atomicAdd(&out[d * 64 + 16 + lm * 3 + 0], S * accC0[r2]);
            atomicAdd(&out[d * 64 + 16 + lm * 3 + 1], S * accC1[r2]);
            atomicAdd(&out[d * 64 + 16 + lm * 3 + 2], S * accC2[r2]);
        }
    }
}

extern "C" void kernel_launch(void* const* d_in, const int* in_sizes, int n_in,
                              void* d_out, int out_size, void* d_ws, size_t ws_size,
                              hipStream_t stream) {
    const float* x        = (const float*)d_in[0];
    const float* edge_vec = (const float*)d_in[1];
    const float* w1       = (const float*)d_in[2];
    const float* w2       = (const float*)d_in[3];
    const int*   src      = (const int*)d_in[4];
    const int*   dst      = (const int*)d_in[5];
    float* out = (float*)d_out;

    hipMemsetAsync(d_out, 0, (size_t)out_size * sizeof(float), stream);

    const int n_tiles = 160000 / TILE_E;   // 2500
    dim3 grid(n_tiles * 4), block(256);
    hipLaunchKernelGGL(se3_fused, grid, block, 0, stream,
                       x, edge_vec, w1, w2, src, dst, out);
}

// Round 2
// 256.332 us; speedup vs baseline: 1.1656x; 1.1656x over previous
//
#include <hip/hip_runtime.h>
#include <hip/hip_bf16.h>

// SE(3)-equivariant layer, MI355X / gfx950 — round 2.
// Round-1 diagnosis: 20.5M fp32 atomicAdds -> 200MB WRITE_SIZE (RMW past L2),
// kernel atomic-bound at ~640 GB/s. Fix: counting-sort edges by dst, then the
// edge kernel (per-path blocks, 64-edge sorted tiles) reduces per-destination
// segments in LDS and issues ~1 coalesced atomic per (segment, column):
// ~1.6M atomics instead of 20.5M.

typedef __attribute__((ext_vector_type(8))) short bf16x8;
typedef __attribute__((ext_vector_type(4))) float f32x4;

#define N_NODES_C 10000
#define N_EDGES_C 160000
#define TILE 64
#define TPB 2                       // tiles per block (amortize W2 staging)
#define NTILES (N_EDGES_C / TILE)   // 2500
#define EBLOCKS (NTILES / TPB)      // 1250

__device__ __forceinline__ float sus_f(float t) { return t > 0.0f ? __expf(-1.0f / t) : 0.0f; }
__device__ __forceinline__ unsigned short f2bf(float f) {
    unsigned int u = __float_as_uint(f);
    u += 0x7FFFu + ((u >> 16) & 1u);
    return (unsigned short)(u >> 16);
}

// ---------- counting sort by dst ----------
__global__ void hist_k(const int* __restrict__ dst, int* __restrict__ hist) {
    int e = blockIdx.x * 256 + threadIdx.x;
    if (e < N_EDGES_C) atomicAdd(&hist[dst[e]], 1);
}

__global__ __launch_bounds__(1024) void scan_k(const int* __restrict__ hist,
                                               int* __restrict__ offsets) {
    __shared__ int tsum[1024];
    const int tid = threadIdx.x, base = tid * 10;
    int loc[10]; int s = 0;
    #pragma unroll
    for (int i = 0; i < 10; ++i) {
        loc[i] = s;
        const int b = base + i;
        s += (b < N_NODES_C) ? hist[b] : 0;
    }
    tsum[tid] = s; __syncthreads();
    for (int d = 1; d < 1024; d <<= 1) {
        const int v = (tid >= d) ? tsum[tid - d] : 0;
        __syncthreads();
        tsum[tid] += v;
        __syncthreads();
    }
    const int off = tsum[tid] - s;  // exclusive
    #pragma unroll
    for (int i = 0; i < 10; ++i) {
        const int b = base + i;
        if (b < N_NODES_C) offsets[b] = off + loc[i];
    }
    if (tid == 1023) offsets[N_NODES_C] = off + s;
}

__global__ void scatter_k(const int* __restrict__ dst, const int* __restrict__ offsets,
                          int* __restrict__ cursor, int* __restrict__ perm,
                          int* __restrict__ dsts) {
    int e = blockIdx.x * 256 + threadIdx.x;
    if (e < N_EDGES_C) {
        const int d = dst[e];
        const int pos = offsets[d] + atomicAdd(&cursor[d], 1);
        perm[pos] = e;
        dsts[pos] = d;
    }
}

// ---------- fused edge kernel ----------
template<int PATH>
__device__ __forceinline__ void edge_body(
    const float* __restrict__ x, const float* __restrict__ edge_vec,
    const float* __restrict__ w1, const float* __restrict__ w2,
    const int* __restrict__ src, const int* __restrict__ perm,
    const int* __restrict__ dsts, float* __restrict__ out,
    unsigned short (*w2t)[72], float* arena, float (*y1l)[4],
    int* dstl, int* srcl, int* segstart, int* nseg_s)
{
    constexpr int NC    = (PATH == 0 || PATH == 3) ? 16 : 48;
    constexpr int CBASE = (PATH == 0 || PATH == 3) ? 0 : 16;

    const int tid = threadIdx.x;
    // arena aliasing (all in floats): embl [0,640) | hl(u16) [640,2944) | feats [2944,6016)
    // summ [0,3072) reuses embl+hl+feats-head after the post-MFMA barrier.
    float* embl = arena;
    unsigned short* hl = (unsigned short*)(arena + 640);   // [64][72] u16, 144B rows
    float* feats = arena + 2944;                           // [64][16] or [64][48]
    float* summ  = arena;                                  // [64][NC]

    // ---- stage W2 path slice transposed -> bf16, packed u32 writes ----
    {
        const float* col = w2 + PATH * 256 + tid;
        #pragma unroll
        for (int k = 0; k < 64; k += 2) {
            const unsigned int lo = f2bf(col[(size_t)k * 1024]);
            const unsigned int hi = f2bf(col[(size_t)(k + 1) * 1024]);
            *(unsigned int*)&w2t[tid][k] = lo | (hi << 16);
        }
    }

    const int lane = tid & 63, wv = tid >> 6, lm = lane & 15, q = lane >> 4;
    const int erow = wv * 16;
    const float C0 = 1.14136f * __expf(2.0f) * 3.1622776601683795f; // * sqrt(10)
    const float S  = 0.17677669529663687f * 0.125f * 0.0625f;       // c * (1/8) * (N/E)

    for (int it = 0; it < TPB; ++it) {
        const int e0 = (blockIdx.x * TPB + it) * TILE;
        __syncthreads();  // prev tile's reduce done before overwriting arena/dstl

        // ---- 1a: radial embedding, unit vector, per-edge meta ----
        for (int idx = tid; idx < TILE * 10; idx += 256) {
            const int e = idx / 10, i = idx - e * 10;
            const int eid = perm[e0 + e];
            const float vx = edge_vec[eid * 3 + 0];
            const float vy = edge_vec[eid * 3 + 1];
            const float vz = edge_vec[eid * 3 + 2];
            const float r = sqrtf(vx * vx + vy * vy + vz * vz);
            const float diff = r * (11.0f / 4.5f) - (float)(i + 1);
            embl[e * 10 + i] = C0 * sus_f(diff + 1.0f) * sus_f(1.0f - diff);
            if (i == 0) {
                const float sc = 1.7320508075688772f / r;
                y1l[e][0] = vx * sc; y1l[e][1] = vy * sc; y1l[e][2] = vz * sc;
                dstl[e] = dsts[e0 + e];
                srcl[e] = src[eid];
            }
        }
        __syncthreads();

        // ---- 1b: h = sqrt(2/10)*relu(emb@W1) -> bf16 hl; gather source feats ----
        for (int idx = tid; idx < TILE * 8; idx += 256) {
            const int e = idx >> 3, j0 = (idx & 7) * 8;
            float acc[8];
            #pragma unroll
            for (int j = 0; j < 8; ++j) acc[j] = 0.0f;
            #pragma unroll
            for (int i = 0; i < 10; ++i) {
                const float ei = embl[e * 10 + i];
                #pragma unroll
                for (int j = 0; j < 8; ++j) acc[j] += ei * w1[i * 64 + j0 + j];
            }
            unsigned int pk[4];
            #pragma unroll
            for (int p = 0; p < 4; ++p) {
                const unsigned int lo = f2bf(fmaxf(acc[2 * p],     0.0f) * 0.4472135954999579f);
                const unsigned int hi = f2bf(fmaxf(acc[2 * p + 1], 0.0f) * 0.4472135954999579f);
                pk[p] = lo | (hi << 16);
            }
            uint4 v; v.x = pk[0]; v.y = pk[1]; v.z = pk[2]; v.w = pk[3];
            *(uint4*)&hl[e * 72 + j0] = v;
        }
        if (PATH == 2) {
            for (int idx = tid; idx < TILE * 48; idx += 256) {
                const int e = idx / 48, c = idx - e * 48;
                feats[e * 48 + c] = x[(size_t)srcl[e] * 64 + 16 + c];
            }
        } else if (PATH == 3) {
            for (int idx = tid; idx < TILE * 16; idx += 256) {
                const int e = idx >> 4, u = idx & 15;
                const float* xs = x + (size_t)srcl[e] * 64 + 16 + u * 3;
                feats[e * 16 + u] = xs[0] * y1l[e][0] + xs[1] * y1l[e][1] + xs[2] * y1l[e][2];
            }
        } else {
            for (int idx = tid; idx < TILE * 16; idx += 256) {
                const int e = idx >> 4, u = idx & 15;
                feats[e * 16 + u] = x[(size_t)srcl[e] * 64 + u];
            }
        }
        __syncthreads();

        // ---- MFMA w-tiles + fused contraction over u ----
        const bf16x8 a0 = *(const bf16x8*)&hl[(erow + lm) * 72 + 8 * q];
        const bf16x8 a1 = *(const bf16x8*)&hl[(erow + lm) * 72 + 32 + 8 * q];
        float accO[4]  = {0.f, 0.f, 0.f, 0.f};
        float accC0[4] = {0.f, 0.f, 0.f, 0.f};
        float accC1[4] = {0.f, 0.f, 0.f, 0.f};
        float accC2[4] = {0.f, 0.f, 0.f, 0.f};
        #pragma unroll 4
        for (int t = 0; t < 16; ++t) {
            const bf16x8 b0 = *(const bf16x8*)&w2t[t * 16 + lm][8 * q];
            const bf16x8 b1 = *(const bf16x8*)&w2t[t * 16 + lm][32 + 8 * q];
            f32x4 wa = {0.f, 0.f, 0.f, 0.f};
            wa = __builtin_amdgcn_mfma_f32_16x16x32_bf16(a0, b0, wa, 0, 0, 0);
            wa = __builtin_amdgcn_mfma_f32_16x16x32_bf16(a1, b1, wa, 0, 0, 0);
            #pragma unroll
            for (int r = 0; r < 4; ++r) {
                const int el = erow + 4 * q + r;
                if (PATH == 2) {
                    accC0[r] += wa[r] * feats[el * 48 + t * 3 + 0];
                    accC1[r] += wa[r] * feats[el * 48 + t * 3 + 1];
                    accC2[r] += wa[r] * feats[el * 48 + t * 3 + 2];
                } else {
                    accO[r] += wa[r] * feats[el * 16 + t];
                }
            }
        }
        __syncthreads();  // hl/feats dead -> summ may overwrite arena

        // ---- per-edge summand into LDS ----
        #pragma unroll
        for (int r = 0; r < 4; ++r) {
            const int el = erow + 4 * q + r;
            if (PATH == 0) {
                summ[el * 16 + lm] = S * accO[r];
            } else if (PATH == 3) {
                summ[el * 16 + lm] = S * 0.5773502691896258f * accO[r];
            } else if (PATH == 1) {
                const float tv = S * accO[r];
                summ[el * 48 + lm * 3 + 0] = tv * y1l[el][0];
                summ[el * 48 + lm * 3 + 1] = tv * y1l[el][1];
                summ[el * 48 + lm * 3 + 2] = tv * y1l[el][2];
            } else {
                summ[el * 48 + lm * 3 + 0] = S * accC0[r];
                summ[el * 48 + lm * 3 + 1] = S * accC1[r];
                summ[el * 48 + lm * 3 + 2] = S * accC2[r];
            }
        }
        // ---- dst-segment boundaries (sorted tile) ----
        if (tid < 64) {
            const int d = dstl[tid];
            const bool flag = (tid == 0) || (d != dstl[tid - 1]);
            const unsigned long long m = __ballot(flag);
            const int sid = (tid == 0) ? 0 : __popcll(m << (64 - tid));
            if (flag) segstart[sid] = tid;
            if (tid == 63) { const int ns = __popcll(m); *nseg_s = ns; segstart[ns] = 64; }
        }
        __syncthreads();

        // ---- segment reduce + one coalesced atomic per (segment, column) ----
        const int ns = *nseg_s;
        for (int i = tid; i < ns * NC; i += 256) {
            const int s = i / NC, c = i - s * NC;
            const int eb = segstart[s], ee = segstart[s + 1];
            float sum = 0.0f;
            for (int e = eb; e < ee; ++e) sum += summ[e * NC + c];
            atomicAdd(&out[(size_t)dstl[eb] * 64 + CBASE + c], sum);
        }
    }
}

__global__ __launch_bounds__(256, 2) void se3_edge(
    const float* __restrict__ x, const float* __restrict__ edge_vec,
    const float* __restrict__ w1, const float* __restrict__ w2,
    const int* __restrict__ src, const int* __restrict__ perm,
    const int* __restrict__ dsts, float* __restrict__ out)
{
    __shared__ unsigned short w2t[256][72];   // 36864 B
    __shared__ float arena[6016];             // 24064 B
    __shared__ float y1l[TILE][4];            // 1024 B
    __shared__ int dstl[TILE];
    __shared__ int srcl[TILE];
    __shared__ int segstart[TILE + 1];
    __shared__ int nseg_s;
    switch (blockIdx.y) {
        case 0:  edge_body<0>(x, edge_vec, w1, w2, src, perm, dsts, out, w2t, arena, y1l, dstl, srcl, segstart, &nseg_s); break;
        case 1:  edge_body<1>(x, edge_vec, w1, w2, src, perm, dsts, out, w2t, arena, y1l, dstl, srcl, segstart, &nseg_s); break;
        case 2:  edge_body<2>(x, edge_vec, w1, w2, src, perm, dsts, out, w2t, arena, y1l, dstl, srcl, segstart, &nseg_s); break;
        default: edge_body<3>(x, edge_vec, w1, w2, src, perm, dsts, out, w2t, arena, y1l, dstl, srcl, segstart, &nseg_s); break;
    }
}

extern "C" void kernel_launch(void* const* d_in, const int* in_sizes, int n_in,
                              void* d_out, int out_size, void* d_ws, size_t ws_size,
                              hipStream_t stream) {
    const float* x        = (const float*)d_in[0];
    const float* edge_vec = (const float*)d_in[1];
    const float* w1       = (const float*)d_in[2];
    const float* w2       = (const float*)d_in[3];
    const int*   src      = (const int*)d_in[4];
    const int*   dst      = (const int*)d_in[5];
    float* out = (float*)d_out;

    // workspace: hist | cursor | offsets | perm | dst_sorted  (~1.4 MB)
    int* hist    = (int*)d_ws;
    int* cursor  = hist + N_NODES_C;
    int* offsets = cursor + N_NODES_C;
    int* perm    = offsets + N_NODES_C + 1;
    int* dsts    = perm + N_EDGES_C;

    hipMemsetAsync(d_out, 0, (size_t)out_size * sizeof(float), stream);
    hipMemsetAsync(d_ws, 0, 2 * N_NODES_C * sizeof(int), stream);

    hipLaunchKernelGGL(hist_k, dim3((N_EDGES_C + 255) / 256), dim3(256), 0, stream, dst, hist);
    hipLaunchKernelGGL(scan_k, dim3(1), dim3(1024), 0, stream, hist, offsets);
    hipLaunchKernelGGL(scatter_k, dim3((N_EDGES_C + 255) / 256), dim3(256), 0, stream,
                       dst, offsets, cursor, perm, dsts);
    hipLaunchKernelGGL(se3_edge, dim3(EBLOCKS, 4), dim3(256), 0, stream,
                       x, edge_vec, w1, w2, src, perm, dsts, out);
}

// Round 3
// 126.817 us; speedup vs baseline: 2.3560x; 2.0213x over previous
//
#include <hip/hip_runtime.h>
#include <hip/hip_bf16.h>

// SE(3)-equivariant layer, MI355X / gfx950 — round 3.
// r2 diagnosis: MfmaUtil 3.7%, VALUBusy 34%, occupancy 22% -> latency/VALU-
// overhead bound (W2 re-staging + in-kernel radial/MLP chains + 6 barriers).
// r3: counting-sort -> prep kernel (streams h/x0/z/x1/y1 per sorted edge,
// pre-swizzled for linear global_load_lds) -> paired-path edge kernel
// ({A,D},{B,C} merge output columns, halving atomics) with double-buffered
// async tile staging under the MFMA loop.

typedef __attribute__((ext_vector_type(8))) short bf16x8;
typedef __attribute__((ext_vector_type(4))) float f32x4;

#define NN 10000
#define NE 160000

__device__ __forceinline__ float sus_f(float t) { return t > 0.0f ? __expf(-1.0f / t) : 0.0f; }
__device__ __forceinline__ unsigned int f2bf(float f) {
    unsigned int u = __float_as_uint(f);
    u += 0x7FFFu + ((u >> 16) & 1u);
    return u >> 16;
}
__device__ __forceinline__ float bf2f(unsigned short v) { return __uint_as_float(((unsigned int)v) << 16); }

#define GL16(g, l) __builtin_amdgcn_global_load_lds( \
    (const __attribute__((address_space(1))) void*)(g), \
    (__attribute__((address_space(3))) void*)(l), 16, 0, 0)

// linear global->LDS stage, 8-wave block, 16B units
__device__ __forceinline__ void stage_lds(const void* g, void* l, int bytes, int wv, int lane) {
    const char* gc = (const char*)g;
    char* lc = (char*)l;
    const int units = bytes >> 4;
    for (int u0 = wv << 6; u0 < units; u0 += 512) {
        if (u0 + lane < units) GL16(gc + (((long)(u0 + lane)) << 4), lc + (u0 << 4));
    }
}

// ---------------- counting sort ----------------
__global__ void hist_k(const int* __restrict__ dst, int* __restrict__ hist,
                       const float* __restrict__ w2, char* __restrict__ w2bf) {
    if (blockIdx.x < 625) {
        const int e = blockIdx.x * 256 + threadIdx.x;
        if (e < NE) atomicAdd(&hist[dst[e]], 1);
    } else {
        // W2 -> bf16, transposed + swizzled: row R (out col), chunk j holds k=8j..8j+7
        const int idx = (blockIdx.x - 625) * 256 + threadIdx.x;  // 0..8191
        const int j = idx >> 10, R = idx & 1023;
        unsigned int pk[4];
        #pragma unroll
        for (int p = 0; p < 4; ++p) {
            const unsigned int lo = f2bf(w2[(size_t)(8 * j + 2 * p) * 1024 + R]);
            const unsigned int hi = f2bf(w2[(size_t)(8 * j + 2 * p + 1) * 1024 + R]);
            pk[p] = lo | (hi << 16);
        }
        uint4 v; v.x = pk[0]; v.y = pk[1]; v.z = pk[2]; v.w = pk[3];
        *(uint4*)(w2bf + R * 128 + ((j ^ (R & 7)) << 4)) = v;
    }
}

__global__ __launch_bounds__(1024) void scan_k(const int* __restrict__ hist,
                                               int* __restrict__ offsets) {
    __shared__ int hl[NN];
    __shared__ int wsum[16];
    const int tid = threadIdx.x;
    for (int i = tid; i < NN; i += 1024) hl[i] = hist[i];
    __syncthreads();
    const int base = tid * 10;
    int loc[10]; int s = 0;
    #pragma unroll
    for (int i = 0; i < 10; ++i) { loc[i] = s; const int b = base + i; s += (b < NN) ? hl[b] : 0; }
    int v = s;
    const int lane = tid & 63, wv = tid >> 6;
    #pragma unroll
    for (int d = 1; d < 64; d <<= 1) { int t2 = __shfl_up(v, d); if (lane >= d) v += t2; }
    if (lane == 63) wsum[wv] = v;
    __syncthreads();
    if (tid < 64) {
        int w = (tid < 16) ? wsum[tid] : 0;
        #pragma unroll
        for (int d = 1; d < 16; d <<= 1) { int t2 = __shfl_up(w, d); if (tid >= d) w += t2; }
        if (tid < 16) wsum[tid] = w;
    }
    __syncthreads();
    const int wexc = (wv == 0) ? 0 : wsum[wv - 1];
    const int texc = wexc + v - s;
    #pragma unroll
    for (int i = 0; i < 10; ++i) { const int b = base + i; if (b < NN) offsets[b] = texc + loc[i]; }
    if (tid == 1023) offsets[NN] = texc + s;
}

__global__ void scatter_k(const int* __restrict__ dst, const int* __restrict__ offsets,
                          int* __restrict__ cursor, int* __restrict__ perm,
                          int* __restrict__ dsts) {
    const int e = blockIdx.x * 256 + threadIdx.x;
    if (e < NE) {
        const int d = dst[e];
        const int pos = offsets[d] + atomicAdd(&cursor[d], 1);
        perm[pos] = e;
        dsts[pos] = d;
    }
}

// ---------------- prep: radial+MLP+gather, streamed per sorted edge ----------------
__global__ __launch_bounds__(256, 4) void prep_k(
    const float* __restrict__ x, const float* __restrict__ edge_vec,
    const float* __restrict__ w1, const int* __restrict__ src,
    const int* __restrict__ perm,
    char* __restrict__ h_bf, char* __restrict__ X0g, char* __restrict__ Zg,
    char* __restrict__ X1g, float* __restrict__ Y1g)
{
    __shared__ float embl[128][10];
    __shared__ float y1l[128][4];
    __shared__ int srcl[128];
    __shared__ float w1l[640];
    const int tid = threadIdx.x;
    const long e0 = (long)blockIdx.x * 128;

    for (int i = tid; i < 640; i += 256) w1l[i] = w1[i];
    if (tid < 128) {
        const int e = tid;
        const int eid = perm[e0 + e];
        const float vx = edge_vec[eid * 3 + 0];
        const float vy = edge_vec[eid * 3 + 1];
        const float vz = edge_vec[eid * 3 + 2];
        const float r = sqrtf(vx * vx + vy * vy + vz * vz);
        const float sc = 1.7320508075688772f / r;
        y1l[e][0] = vx * sc; y1l[e][1] = vy * sc; y1l[e][2] = vz * sc; y1l[e][3] = 0.f;
        *(float4*)&Y1g[(e0 + e) * 4] = make_float4(vx * sc, vy * sc, vz * sc, 0.f);
        srcl[e] = src[eid];
        const float C0 = 1.14136f * __expf(2.0f) * 3.1622776601683795f; // * sqrt(10)
        #pragma unroll
        for (int i = 0; i < 10; ++i) {
            const float diff = r * (11.0f / 4.5f) - (float)(i + 1);
            embl[e][i] = C0 * sus_f(diff + 1.0f) * sus_f(1.0f - diff);
        }
    }
    __syncthreads();
    // h = sqrt(2/10)*relu(emb@W1) -> bf16, swizzled slot j^(e&7)
    for (int idx = tid; idx < 1024; idx += 256) {
        const int e = idx >> 3, j = idx & 7;
        float acc[8];
        #pragma unroll
        for (int jj = 0; jj < 8; ++jj) acc[jj] = 0.0f;
        #pragma unroll
        for (int i = 0; i < 10; ++i) {
            const float ei = embl[e][i];
            #pragma unroll
            for (int jj = 0; jj < 8; ++jj) acc[jj] += ei * w1l[i * 64 + j * 8 + jj];
        }
        unsigned int pk[4];
        #pragma unroll
        for (int p = 0; p < 4; ++p) {
            const unsigned int lo = f2bf(fmaxf(acc[2 * p],     0.0f) * 0.4472135954999579f);
            const unsigned int hi = f2bf(fmaxf(acc[2 * p + 1], 0.0f) * 0.4472135954999579f);
            pk[p] = lo | (hi << 16);
        }
        uint4 v; v.x = pk[0]; v.y = pk[1]; v.z = pk[2]; v.w = pk[3];
        *(uint4*)(h_bf + (e0 + e) * 128 + ((j ^ (e & 7)) << 4)) = v;
    }
    // X0 bf16 [18]-u16 rows
    for (int idx = tid; idx < 1024; idx += 256) {
        const int e = idx >> 3, p = idx & 7;
        const int s = srcl[e];
        const float2 ab = *(const float2*)&x[(size_t)s * 64 + 2 * p];
        *(unsigned int*)(X0g + (e0 + e) * 36 + p * 4) = f2bf(ab.x) | (f2bf(ab.y) << 16);
    }
    // Z bf16 [18]-u16 rows: z[u] = x1[u].y1
    for (int idx = tid; idx < 1024; idx += 256) {
        const int e = idx >> 3, p = idx & 7;
        const int s = srcl[e];
        const float* xp = x + (size_t)s * 64 + 16 + 6 * p;
        const float z0 = xp[0] * y1l[e][0] + xp[1] * y1l[e][1] + xp[2] * y1l[e][2];
        const float z1 = xp[3] * y1l[e][0] + xp[4] * y1l[e][1] + xp[5] * y1l[e][2];
        *(unsigned int*)(Zg + (e0 + e) * 36 + p * 4) = f2bf(z0) | (f2bf(z1) << 16);
    }
    // X1 f32 [52]-f32 rows (16B aligned)
    for (int idx = tid; idx < 128 * 12; idx += 256) {
        const int e = idx / 12, qd = idx - e * 12;
        const int s = srcl[e];
        const float4 v = *(const float4*)&x[(size_t)s * 64 + 16 + 4 * qd];
        *(float4*)(X1g + (e0 + e) * 208 + qd * 16) = v;
    }
}

// ---------------- fused edge kernel (paired paths) ----------------
// buf layout: hl [128][128B] @0 | X0 [128][36B] @16384 | F1(Z 4608 / X1 26624) @20992 | dstl @47616
#define BUF_SZ 48128

__global__ __launch_bounds__(512, 2) void se3_edge2(
    const char* __restrict__ w2bf, const char* __restrict__ h_bf,
    const char* __restrict__ X0g, const char* __restrict__ Zg,
    const char* __restrict__ X1g, const float* __restrict__ Y1g,
    const int* __restrict__ dsts, float* __restrict__ out)
{
    __shared__ __align__(16) char w2lds[65536];
    __shared__ __align__(16) char bufs[2][BUF_SZ];
    __shared__ int segst[2][66];
    __shared__ int nseg[2];

    const int tid = threadIdx.x, lane = tid & 63, wv = tid >> 6;
    const int lm = lane & 15, q = lane >> 4;
    const int bx = blockIdx.x;
    const int pair = (bx & 1) ^ ((bx >> 8) & 1);
    const int tb = bx >> 1;              // 0..249
    const int s0 = (q ^ (lm & 7)) << 4;  // b0 slot byte
    const int s1 = s0 ^ 64;              // b1 slot byte (chunk 4+q)
    const int erow = wv << 4;

    const char* w2p0 = w2lds;
    const char* w2p1 = w2lds + 32768;
    {
        const int pa = pair ? 1 : 0, pb = pair ? 2 : 3;
        stage_lds(w2bf + pa * 32768, w2lds, 32768, wv, lane);
        stage_lds(w2bf + pb * 32768, w2lds + 32768, 32768, wv, lane);
        const long e0 = (long)tb * 5 * 128;
        stage_lds(h_bf + e0 * 128, bufs[0], 16384, wv, lane);
        stage_lds(X0g + e0 * 36, bufs[0] + 16384, 4608, wv, lane);
        if (pair) stage_lds(X1g + e0 * 208, bufs[0] + 20992, 26624, wv, lane);
        else      stage_lds(Zg  + e0 * 36,  bufs[0] + 20992, 4608,  wv, lane);
        stage_lds((const char*)(dsts + e0), bufs[0] + 47616, 512, wv, lane);
    }
    __syncthreads();

    const float S = 0.17677669529663687f * 0.125f * 0.0625f; // c * (1/8) * (N/E)

    for (int tt = 0; tt < 5; ++tt) {
        char* buf = bufs[tt & 1];
        const long gt = (long)tb * 5 + tt;
        const long e0 = gt * 128;
        if (tt < 4) {  // issue next tile's stage early: flies under compute
            char* nb = bufs[(tt & 1) ^ 1];
            const long ne0 = e0 + 128;
            stage_lds(h_bf + ne0 * 128, nb, 16384, wv, lane);
            stage_lds(X0g + ne0 * 36, nb + 16384, 4608, wv, lane);
            if (pair) stage_lds(X1g + ne0 * 208, nb + 20992, 26624, wv, lane);
            else      stage_lds(Zg  + ne0 * 36,  nb + 20992, 4608,  wv, lane);
            stage_lds((const char*)(dsts + ne0), nb + 47616, 512, wv, lane);
        }
        const char* hl = buf;
        const int arow = erow + lm;
        const bf16x8 a0 = *(const bf16x8*)(hl + arow * 128 + s0);
        const bf16x8 a1 = *(const bf16x8*)(hl + arow * 128 + s1);
        const unsigned short* X0l = (const unsigned short*)(buf + 16384);
        const int* dstl = (const int*)(buf + 47616);

        float ac0[4] = {0,0,0,0}, ac1[4] = {0,0,0,0}, ac2[4] = {0,0,0,0}, ac3[4] = {0,0,0,0};

        if (pair == 0) {  // {A, D}
            const unsigned short* Zl = (const unsigned short*)(buf + 20992);
            #pragma unroll 4
            for (int t = 0; t < 16; ++t) {
                const int rowb = (t * 16 + lm) << 7;
                const bf16x8 b00 = *(const bf16x8*)(w2p0 + rowb + s0);
                const bf16x8 b01 = *(const bf16x8*)(w2p0 + rowb + s1);
                const bf16x8 b10 = *(const bf16x8*)(w2p1 + rowb + s0);
                const bf16x8 b11 = *(const bf16x8*)(w2p1 + rowb + s1);
                f32x4 wA = {0.f,0.f,0.f,0.f};
                wA = __builtin_amdgcn_mfma_f32_16x16x32_bf16(a0, b00, wA, 0,0,0);
                wA = __builtin_amdgcn_mfma_f32_16x16x32_bf16(a1, b01, wA, 0,0,0);
                f32x4 wD = {0.f,0.f,0.f,0.f};
                wD = __builtin_amdgcn_mfma_f32_16x16x32_bf16(a0, b10, wD, 0,0,0);
                wD = __builtin_amdgcn_mfma_f32_16x16x32_bf16(a1, b11, wD, 0,0,0);
                #pragma unroll
                for (int r = 0; r < 4; ++r) {
                    const int el = erow + 4 * q + r;
                    ac0[r] += wA[r] * bf2f(X0l[el * 18 + t]);
                    ac1[r] += wD[r] * bf2f(Zl[el * 18 + t]);
                }
            }
            float* summ32 = (float*)buf;  // aliases hl (wave-private rows)
            #pragma unroll
            for (int r = 0; r < 4; ++r) {
                const int el = erow + 4 * q + r;
                summ32[el * 17 + lm] = S * (ac0[r] + 0.5773502691896258f * ac1[r]);
            }
        } else {          // {B, C}
            const float* X1l = (const float*)(buf + 20992);
            #pragma unroll 4
            for (int t = 0; t < 16; ++t) {
                const int rowb = (t * 16 + lm) << 7;
                const bf16x8 b00 = *(const bf16x8*)(w2p0 + rowb + s0);
                const bf16x8 b01 = *(const bf16x8*)(w2p0 + rowb + s1);
                const bf16x8 b10 = *(const bf16x8*)(w2p1 + rowb + s0);
                const bf16x8 b11 = *(const bf16x8*)(w2p1 + rowb + s1);
                f32x4 wB = {0.f,0.f,0.f,0.f};
                wB = __builtin_amdgcn_mfma_f32_16x16x32_bf16(a0, b00, wB, 0,0,0);
                wB = __builtin_amdgcn_mfma_f32_16x16x32_bf16(a1, b01, wB, 0,0,0);
                f32x4 wC = {0.f,0.f,0.f,0.f};
                wC = __builtin_amdgcn_mfma_f32_16x16x32_bf16(a0, b10, wC, 0,0,0);
                wC = __builtin_amdgcn_mfma_f32_16x16x32_bf16(a1, b11, wC, 0,0,0);
                #pragma unroll
                for (int r = 0; r < 4; ++r) {
                    const int el = erow + 4 * q + r;
                    ac0[r] += wB[r] * bf2f(X0l[el * 18 + t]);
                    ac1[r] += wC[r] * X1l[el * 52 + 3 * t + 0];
                    ac2[r] += wC[r] * X1l[el * 52 + 3 * t + 1];
                    ac3[r] += wC[r] * X1l[el * 52 + 3 * t + 2];
                }
            }
            unsigned short* summ16 = (unsigned short*)buf;  // aliases hl
            #pragma unroll
            for (int r = 0; r < 4; ++r) {
                const int el = erow + 4 * q + r;
                const float4 y = *(const float4*)&Y1g[(e0 + el) * 4];
                const float b = S * ac0[r];
                summ16[el * 49 + 3 * lm + 0] = (unsigned short)f2bf(b * y.x + S * ac1[r]);
                summ16[el * 49 + 3 * lm + 1] = (unsigned short)f2bf(b * y.y + S * ac2[r]);
                summ16[el * 49 + 3 * lm + 2] = (unsigned short)f2bf(b * y.z + S * ac3[r]);
            }
        }
        // segment boundaries per 64-edge half (waves 0,1)
        if (wv < 2) {
            const int base = wv << 6;
            const int d = dstl[base + lane];
            const bool flag = (lane == 0) || (d != dstl[base + lane - 1]);
            const unsigned long long m = __ballot(flag);
            const int sid = (lane == 0) ? 0 : __popcll(m & ((1ull << lane) - 1ull));
            if (flag) segst[wv][sid] = base + lane;
            if (lane == 63) { const int ns = __popcll(m); nseg[wv] = ns; segst[wv][ns] = base + 64; }
        }
        __syncthreads();
        // segment reduce + coalesced atomics
        const int nsa = nseg[0], nsb = nseg[1];
        if (pair == 0) {
            const float* summ32 = (const float*)buf;
            const int total = (nsa + nsb) * 16;
            for (int i = tid; i < total; i += 512) {
                const int sg = i >> 4, c = i & 15;
                const int hh = sg >= nsa;
                const int sl = hh ? sg - nsa : sg;
                const int eb = segst[hh][sl], ee = segst[hh][sl + 1];
                float sum = 0.f;
                for (int e = eb; e < ee; ++e) sum += summ32[e * 17 + c];
                atomicAdd(&out[(size_t)dstl[eb] * 64 + c], sum);
            }
        } else {
            const unsigned short* summ16 = (const unsigned short*)buf;
            const int total = (nsa + nsb) * 48;
            for (int i = tid; i < total; i += 512) {
                const int sg = i / 48, c = i - sg * 48;
                const int hh = sg >= nsa;
                const int sl = hh ? sg - nsa : sg;
                const int eb = segst[hh][sl], ee = segst[hh][sl + 1];
                float sum = 0.f;
                for (int e = eb; e < ee; ++e) sum += bf2f(summ16[e * 49 + c]);
                atomicAdd(&out[(size_t)dstl[eb] * 64 + 16 + c], sum);
            }
        }
        __syncthreads();
    }
}

// ---------------- fallback (round-2 path, small-ws) ----------------
#define FBT 64
template<int PATH>
__device__ __forceinline__ void fb_body(
    const float* __restrict__ x, const float* __restrict__ edge_vec,
    const float* __restrict__ w1, const float* __restrict__ w2,
    const int* __restrict__ src, const int* __restrict__ perm,
    const int* __restrict__ dsts, float* __restrict__ out,
    unsigned short (*w2t)[72], float* arena, float (*y1l)[4],
    int* dstl, int* srcl, int* segstart, int* nseg_s)
{
    constexpr int NC    = (PATH == 0 || PATH == 3) ? 16 : 48;
    constexpr int CBASE = (PATH == 0 || PATH == 3) ? 0 : 16;
    const int tid = threadIdx.x;
    float* embl = arena;
    unsigned short* hl = (unsigned short*)(arena + 640);
    float* feats = arena + 2944;
    float* summ  = arena;
    {
        const float* col = w2 + PATH * 256 + tid;
        #pragma unroll
        for (int k = 0; k < 64; k += 2) {
            const unsigned int lo = f2bf(col[(size_t)k * 1024]);
            const unsigned int hi = f2bf(col[(size_t)(k + 1) * 1024]);
            *(unsigned int*)&w2t[tid][k] = lo | (hi << 16);
        }
    }
    const int lane = tid & 63, wv = tid >> 6, lm = lane & 15, q = lane >> 4;
    const int erow = wv * 16;
    const float C0 = 1.14136f * __expf(2.0f) * 3.1622776601683795f;
    const float S  = 0.17677669529663687f * 0.125f * 0.0625f;
    for (int it = 0; it < 2; ++it) {
        const int e0 = (blockIdx.x * 2 + it) * FBT;
        __syncthreads();
        for (int idx = tid; idx < FBT * 10; idx += 256) {
            const int e = idx / 10, i = idx - e * 10;
            const int eid = perm[e0 + e];
            const float vx = edge_vec[eid * 3 + 0], vy = edge_vec[eid * 3 + 1], vz = edge_vec[eid * 3 + 2];
            const float r = sqrtf(vx * vx + vy * vy + vz * vz);
            const float diff = r * (11.0f / 4.5f) - (float)(i + 1);
            embl[e * 10 + i] = C0 * sus_f(diff + 1.0f) * sus_f(1.0f - diff);
            if (i == 0) {
                const float sc = 1.7320508075688772f / r;
                y1l[e][0] = vx * sc; y1l[e][1] = vy * sc; y1l[e][2] = vz * sc;
                dstl[e] = dsts[e0 + e];
                srcl[e] = src[eid];
            }
        }
        __syncthreads();
        for (int idx = tid; idx < FBT * 8; idx += 256) {
            const int e = idx >> 3, j0 = (idx & 7) * 8;
            float acc[8];
            #pragma unroll
            for (int j = 0; j < 8; ++j) acc[j] = 0.0f;
            #pragma unroll
            for (int i = 0; i < 10; ++i) {
                const float ei = embl[e * 10 + i];
                #pragma unroll
                for (int j = 0; j < 8; ++j) acc[j] += ei * w1[i * 64 + j0 + j];
            }
            unsigned int pk[4];
            #pragma unroll
            for (int p = 0; p < 4; ++p) {
                const unsigned int lo = f2bf(fmaxf(acc[2 * p],     0.0f) * 0.4472135954999579f);
                const unsigned int hi = f2bf(fmaxf(acc[2 * p + 1], 0.0f) * 0.4472135954999579f);
                pk[p] = lo | (hi << 16);
            }
            uint4 v; v.x = pk[0]; v.y = pk[1]; v.z = pk[2]; v.w = pk[3];
            *(uint4*)&hl[e * 72 + j0] = v;
        }
        if (PATH == 2) {
            for (int idx = tid; idx < FBT * 48; idx += 256) {
                const int e = idx / 48, c = idx - e * 48;
                feats[e * 48 + c] = x[(size_t)srcl[e] * 64 + 16 + c];
            }
        } else if (PATH == 3) {
            for (int idx = tid; idx < FBT * 16; idx += 256) {
                const int e = idx >> 4, u = idx & 15;
                const float* xs = x + (size_t)srcl[e] * 64 + 16 + u * 3;
                feats[e * 16 + u] = xs[0] * y1l[e][0] + xs[1] * y1l[e][1] + xs[2] * y1l[e][2];
            }
        } else {
            for (int idx = tid; idx < FBT * 16; idx += 256) {
                const int e = idx >> 4, u = idx & 15;
                feats[e * 16 + u] = x[(size_t)srcl[e] * 64 + u];
            }
        }
        __syncthreads();
        const bf16x8 a0 = *(const bf16x8*)&hl[(erow + lm) * 72 + 8 * q];
        const bf16x8 a1 = *(const bf16x8*)&hl[(erow + lm) * 72 + 32 + 8 * q];
        float accO[4] = {0.f,0.f,0.f,0.f}, accC0[4] = {0.f,0.f,0.f,0.f};
        float accC1[4] = {0.f,0.f,0.f,0.f}, accC2[4] = {0.f,0.f,0.f,0.f};
        #pragma unroll 4
        for (int t = 0; t < 16; ++t) {
            const bf16x8 b0 = *(const bf16x8*)&w2t[t * 16 + lm][8 * q];
            const bf16x8 b1 = *(const bf16x8*)&w2t[t * 16 + lm][32 + 8 * q];
            f32x4 wa = {0.f,0.f,0.f,0.f};
            wa = __builtin_amdgcn_mfma_f32_16x16x32_bf16(a0, b0, wa, 0, 0, 0);
            wa = __builtin_amdgcn_mfma_f32_16x16x32_bf16(a1, b1, wa, 0, 0, 0);
            #pragma unroll
            for (int r = 0; r < 4; ++r) {
                const int el = erow + 4 * q + r;
                if (PATH == 2) {
                    accC0[r] += wa[r] * feats[el * 48 + t * 3 + 0];
                    accC1[r] += wa[r] * feats[el * 48 + t * 3 + 1];
                    accC2[r] += wa[r] * feats[el * 48 + t * 3 + 2];
                } else {
                    accO[r] += wa[r] * feats[el * 16 + t];
                }
            }
        }
        __syncthreads();
        #pragma unroll
        for (int r = 0; r < 4; ++r) {
            const int el = erow + 4 * q + r;
            if (PATH == 0) summ[el * 16 + lm] = S * accO[r];
            else if (PATH == 3) summ[el * 16 + lm] = S * 0.5773502691896258f * accO[r];
            else if (PATH == 1) {
                const float tv = S * accO[r];
                summ[el * 48 + lm * 3 + 0] = tv * y1l[el][0];
                summ[el * 48 + lm * 3 + 1] = tv * y1l[el][1];
                summ[el * 48 + lm * 3 + 2] = tv * y1l[el][2];
            } else {
                summ[el * 48 + lm * 3 + 0] = S * accC0[r];
                summ[el * 48 + lm * 3 + 1] = S * accC1[r];
                summ[el * 48 + lm * 3 + 2] = S * accC2[r];
            }
        }
        if (tid < 64) {
            const int d = dstl[tid];
            const bool flag = (tid == 0) || (d != dstl[tid - 1]);
            const unsigned long long m = __ballot(flag);
            const int sid = (tid == 0) ? 0 : __popcll(m & ((1ull << tid) - 1ull));
            if (flag) segstart[sid] = tid;
            if (tid == 63) { const int ns = __popcll(m); *nseg_s = ns; segstart[ns] = 64; }
        }
        __syncthreads();
        const int ns = *nseg_s;
        for (int i = tid; i < ns * NC; i += 256) {
            const int s = i / NC, c = i - s * NC;
            const int eb = segstart[s], ee = segstart[s + 1];
            float sum = 0.0f;
            for (int e = eb; e < ee; ++e) sum += summ[e * NC + c];
            atomicAdd(&out[(size_t)dstl[eb] * 64 + CBASE + c], sum);
        }
    }
}

__global__ __launch_bounds__(256, 2) void fb_edge(
    const float* __restrict__ x, const float* __restrict__ edge_vec,
    const float* __restrict__ w1, const float* __restrict__ w2,
    const int* __restrict__ src, const int* __restrict__ perm,
    const int* __restrict__ dsts, float* __restrict__ out)
{
    __shared__ unsigned short w2t[256][72];
    __shared__ float arena[6016];
    __shared__ float y1l[FBT][4];
    __shared__ int dstl[FBT];
    __shared__ int srcl[FBT];
    __shared__ int segstart[FBT + 1];
    __shared__ int nseg_s;
    switch (blockIdx.y) {
        case 0:  fb_body<0>(x, edge_vec, w1, w2, src, perm, dsts, out, w2t, arena, y1l, dstl, srcl, segstart, &nseg_s); break;
        case 1:  fb_body<1>(x, edge_vec, w1, w2, src, perm, dsts, out, w2t, arena, y1l, dstl, srcl, segstart, &nseg_s); break;
        case 2:  fb_body<2>(x, edge_vec, w1, w2, src, perm, dsts, out, w2t, arena, y1l, dstl, srcl, segstart, &nseg_s); break;
        default: fb_body<3>(x, edge_vec, w1, w2, src, perm, dsts, out, w2t, arena, y1l, dstl, srcl, segstart, &nseg_s); break;
    }
}

// ---------------- host ----------------
extern "C" void kernel_launch(void* const* d_in, const int* in_sizes, int n_in,
                              void* d_out, int out_size, void* d_ws, size_t ws_size,
                              hipStream_t stream) {
    const float* x        = (const float*)d_in[0];
    const float* edge_vec = (const float*)d_in[1];
    const float* w1       = (const float*)d_in[2];
    const float* w2       = (const float*)d_in[3];
    const int*   src      = (const int*)d_in[4];
    const int*   dst      = (const int*)d_in[5];
    float* out = (float*)d_out;

    char* ws = (char*)d_ws;
    size_t off = 0;
    auto alloc = [&](size_t n) -> char* {
        off = (off + 255) & ~(size_t)255;
        char* p = ws + off; off += n; return p;
    };
    int* hist    = (int*)alloc(40000);
    int* cursor  = (int*)alloc(40000);
    int* offsets = (int*)alloc(40004);
    int* perm    = (int*)alloc(640000);
    int* dsts    = (int*)alloc(640000);
    char* w2bf   = alloc(131072);
    char* h_bf   = alloc((size_t)NE * 128);
    char* X0g    = alloc((size_t)NE * 36);
    char* Zg     = alloc((size_t)NE * 36);
    float* Y1g   = (float*)alloc((size_t)NE * 16);
    char* X1g    = alloc((size_t)NE * 208);
    const bool big = (off <= ws_size);

    hipMemsetAsync(d_out, 0, (size_t)out_size * sizeof(float), stream);
    hipMemsetAsync(d_ws, 0, 81408, stream);  // hist + cursor

    if (big) {
        hipLaunchKernelGGL(hist_k, dim3(657), dim3(256), 0, stream, dst, hist, w2, w2bf);
        hipLaunchKernelGGL(scan_k, dim3(1), dim3(1024), 0, stream, hist, offsets);
        hipLaunchKernelGGL(scatter_k, dim3(625), dim3(256), 0, stream, dst, offsets, cursor, perm, dsts);
        hipLaunchKernelGGL(prep_k, dim3(1250), dim3(256), 0, stream,
                           x, edge_vec, w1, src, perm, h_bf, X0g, Zg, X1g, Y1g);
        hipLaunchKernelGGL(se3_edge2, dim3(500), dim3(512), 0, stream,
                           w2bf, h_bf, X0g, Zg, X1g, Y1g, dsts, out);
    } else {
        hipLaunchKernelGGL(hist_k, dim3(625), dim3(256), 0, stream, dst, hist, w2, w2bf);
        hipLaunchKernelGGL(scan_k, dim3(1), dim3(1024), 0, stream, hist, offsets);
        hipLaunchKernelGGL(scatter_k, dim3(625), dim3(256), 0, stream, dst, offsets, cursor, perm, dsts);
        hipLaunchKernelGGL(fb_edge, dim3(1250, 4), dim3(256), 0, stream,
                           x, edge_vec, w1, w2, src, perm, dsts, out);
    }
}